// Round 5
// baseline (183.245 us; speedup 1.0000x reference)
//
#include <hip/hip_runtime.h>
#include <math.h>

// ---------------------------------------------------------------------------
// B=4096. conv1 (64,5,7) pad3 + relu + pool4 -> h1 (64,96)
//         conv2 (128,64,5) pad2 + relu + pool4 -> feat (128,24)
//         fc: only cols 0..5 of (404,3072) + tau = feat·(L_w@fc_w) + const.
// Split-bf16 MFMA (hi+lo, 3 mfma/product, err ~2^-18/term — REQUIRED: the
// rollout amplifies param error ~1e6x; single fp16/bf16 would fail).
// conv2 = 5 shifted GEMMs (tap dk) over K=64(ic); h1 stored PACKED (hi|lo
// u32) [100][68] -> 2-way-free b128 reads, b32 writes, 36.7 KB LDS
// => 4 blocks/CU with regs<=128 (__launch_bounds__(256,4)).
// C/D layout (m89): col=lane&15 -> oc, row=(lane>>4)*4+reg -> pos.
// ---------------------------------------------------------------------------

typedef short bf16x8 __attribute__((ext_vector_type(8)));
typedef float f32x4  __attribute__((ext_vector_type(4)));
typedef int   i32x4  __attribute__((ext_vector_type(4)));

union Frag { int u[4]; i32x4 q; bf16x8 v; };

__device__ __forceinline__ unsigned bf16_rne(float f) {
    unsigned u = __float_as_uint(f);
    return (u + 0x7fffu + ((u >> 16) & 1u)) >> 16;
}
__device__ __forceinline__ unsigned packsplit(float f) {
    unsigned hi = bf16_rne(f);
    float lo = f - __uint_as_float(hi << 16);
    return (hi << 16) | bf16_rne(lo);
}

// ---------------------------------------------------------------------------
// Kernel 0a: fc7 table. 12 blocks x 1024 threads; j-loop split 4 ways.
// ---------------------------------------------------------------------------
__global__ void precompute_fc(const float* __restrict__ fc_w,
                              const float* __restrict__ L_w,
                              float* __restrict__ fc7) {
    __shared__ float part[3][256];
    const int t = threadIdx.x, k = blockIdx.x * 256 + (t & 255), jc = t >> 8;
    const int j0 = jc * 101;
    float s = 0.f;
    #pragma unroll 4
    for (int j = j0; j < j0 + 101; ++j) s += L_w[j] * fc_w[j * 3072 + k];
    if (jc) part[jc - 1][t & 255] = s;
    __syncthreads();
    if (jc == 0) {
        const int kk = t & 255;
        float r[8];
        #pragma unroll
        for (int j = 0; j < 6; ++j) r[j] = fc_w[j * 3072 + k];
        r[6] = s + part[0][kk] + part[1][kk] + part[2][kk];
        r[7] = 0.f;
        #pragma unroll
        for (int j = 0; j < 8; ++j) fc7[k * 8 + j] = r[j];
    }
}

// ---------------------------------------------------------------------------
// Kernel 0b: taub + weight-fragment tables (hi/lo). 21 blocks x 256.
//  wfrag1: [split2][ks2][oct4][lane64][4u32]       (conv1, K'=64 padded)
//  wfrag2: [split2][dk5][ks2][oct8][lane64][4u32]  (conv2 taps, K=64=ic)
// ---------------------------------------------------------------------------
__global__ void precompute_frags(const float* __restrict__ w1,
                                 const float* __restrict__ w2,
                                 const float* __restrict__ fc_b,
                                 const float* __restrict__ L_w,
                                 const float* __restrict__ L_b,
                                 float* __restrict__ taub,
                                 unsigned* __restrict__ wfrag1,
                                 unsigned* __restrict__ wfrag2) {
    const int t = threadIdx.x, bb = blockIdx.x;
    if (bb == 0) {
        if (t < 64) {
            float s = 0.f;
            for (int j = t; j < 404; j += 64) s += L_w[j] * fc_b[j];
            #pragma unroll
            for (int off = 32; off; off >>= 1) s += __shfl_down(s, off);
            if (t == 0) taub[0] = s + L_b[0];
        }
        for (int it = t; it < 1024; it += 256) {    // conv1 frags
            const int split = it >> 9, ks = (it >> 8) & 1,
                      oct = (it >> 6) & 3, lane = it & 63;
            const int oc = oct * 16 + (lane & 15);
            unsigned h[8];
            #pragma unroll
            for (int j = 0; j < 8; ++j) {
                const int kp = ks * 32 + (lane >> 4) * 8 + j;  // k' = dk*8+ic
                const int dk = kp >> 3, ic = kp & 7;
                float v = (ic < 5 && dk < 7) ? w1[oc * 35 + ic * 7 + dk] : 0.f;
                unsigned hb = bf16_rne(v);
                if (split) hb = bf16_rne(v - __uint_as_float(hb << 16));
                h[j] = hb;
            }
            #pragma unroll
            for (int wj = 0; wj < 4; ++wj)
                wfrag1[it * 4 + wj] = (h[2 * wj + 1] << 16) | h[2 * wj];
        }
    } else {                                        // conv2 tap frags: 10240
        const int base = (bb - 1) * 512;
        #pragma unroll
        for (int r = 0; r < 2; ++r) {
            const int it = base + r * 256 + t;
            const int split = it / 5120, rem = it % 5120;
            const int dk = rem >> 10, rem2 = rem & 1023;
            const int ks = rem2 >> 9, oct = (rem2 >> 6) & 7, lane = rem2 & 63;
            const int oc = oct * 16 + (lane & 15);
            unsigned h[8];
            #pragma unroll
            for (int j = 0; j < 8; ++j) {
                const int ic = ks * 32 + (lane >> 4) * 8 + j;   // k = ic
                const float v = w2[oc * 320 + ic * 5 + dk];
                unsigned hb = bf16_rne(v);
                if (split) hb = bf16_rne(v - __uint_as_float(hb << 16));
                h[j] = hb;
            }
            #pragma unroll
            for (int wj = 0; wj < 4; ++wj)
                wfrag2[it * 4 + wj] = (h[2 * wj + 1] << 16) | h[2 * wj];
        }
    }
}

// ---------------------------------------------------------------------------
// Kernel 1: fused conv1+conv2+fc, one batch per block, 4 blocks/CU.
// LDS (36736 B): lds_in u32[6][392] (row5=zeros), h1p u32[100][68] packed
// hi|lo (rows 0,1,98,99 halo-zero), red f32[32].
// ---------------------------------------------------------------------------
__global__ __launch_bounds__(256, 4) void fused_kernel(
    const float* __restrict__ input,
    const float* __restrict__ b1,
    const float* __restrict__ b2,
    const unsigned* __restrict__ wfrag1,
    const unsigned* __restrict__ wfrag2,
    const float* __restrict__ fc7,
    const float* __restrict__ fc_b,
    const float* __restrict__ taubp,
    float* __restrict__ params)
{
    __shared__ unsigned lds_in[2352];
    __shared__ unsigned h1p[6800];
    __shared__ float red[32];

    const int t = threadIdx.x, b = blockIdx.x;
    const int lane = t & 63, w = t >> 6;
    const int lg = lane >> 4, lr = lane & 15;

    // ---- zero lds_in + h1p halo rows (0,1,98,99) ----
    for (int i = t; i < 2352; i += 256) lds_in[i] = 0u;
    for (int i = t; i < 272; i += 256) {
        const int r = i / 68, wd = i - r * 68;
        const int row = (r < 2) ? r : 96 + r;
        h1p[row * 68 + wd] = 0u;
    }
    __syncthreads();
    const float* inb = input + (size_t)b * 1920;
    for (int i = t; i < 1920; i += 256) {
        const int ic = i / 384, x = i - ic * 384;
        lds_in[ic * 392 + 3 + x] = packsplit(inb[i]);
    }
    __syncthreads();

    // ---------------- conv1: C[pos=384][oc=64], K'=64 ----------------
    const i32x4* w1f = (const i32x4*)wfrag1;
    float b1v[4];
    #pragma unroll
    for (int oct = 0; oct < 4; ++oct) b1v[oct] = b1[oct * 16 + lr];

    const unsigned* aB1 = lds_in + w * 96 + lr + lg;
    #pragma unroll
    for (int mt = 0; mt < 6; ++mt) {
        f32x4 acc[4];
        #pragma unroll
        for (int oct = 0; oct < 4; ++oct) acc[oct] = (f32x4){0.f, 0.f, 0.f, 0.f};
        #pragma unroll
        for (int ks = 0; ks < 2; ++ks) {
            Frag bh[4], bl[4];
            #pragma unroll
            for (int oct = 0; oct < 4; ++oct) {
                bh[oct].q = w1f[(ks * 4 + oct) * 64 + lane];
                bl[oct].q = w1f[((2 + ks) * 4 + oct) * 64 + lane];
            }
            unsigned p[8];
            #pragma unroll
            for (int j = 0; j < 8; ++j) {
                const int jr = (j < 5) ? j : 5;           // row5 = zeros
                p[j] = aB1[mt * 16 + ks * 4 + jr * 392];
            }
            Frag ah, al;
            #pragma unroll
            for (int wj = 0; wj < 4; ++wj) {
                ah.u[wj] = __builtin_amdgcn_perm(p[2*wj+1], p[2*wj], 0x07060302u);
                al.u[wj] = __builtin_amdgcn_perm(p[2*wj+1], p[2*wj], 0x05040100u);
            }
            #pragma unroll
            for (int oct = 0; oct < 4; ++oct)
                acc[oct] = __builtin_amdgcn_mfma_f32_16x16x32_bf16(ah.v, bh[oct].v, acc[oct], 0, 0, 0);
            #pragma unroll
            for (int oct = 0; oct < 4; ++oct)
                acc[oct] = __builtin_amdgcn_mfma_f32_16x16x32_bf16(ah.v, bl[oct].v, acc[oct], 0, 0, 0);
            #pragma unroll
            for (int oct = 0; oct < 4; ++oct)
                acc[oct] = __builtin_amdgcn_mfma_f32_16x16x32_bf16(al.v, bh[oct].v, acc[oct], 0, 0, 0);
        }
        const int c = (w * 6 + mt) * 4 + lg;
        #pragma unroll
        for (int oct = 0; oct < 4; ++oct) {
            float s = 0.f;
            #pragma unroll
            for (int r4 = 0; r4 < 4; ++r4) s += fmaxf(acc[oct][r4] + b1v[oct], 0.f);
            h1p[(c + 2) * 68 + oct * 16 + lr] = packsplit(0.25f * s);
        }
    }
    __syncthreads();

    // -------- conv2: 5 taps x K=64, C[pos=96][oc=128] --------
    const int mbase = (w & 1) * 3, nbase = (w >> 1) * 4;
    f32x4 acc2[3][4];
    #pragma unroll
    for (int mt = 0; mt < 3; ++mt)
        #pragma unroll
        for (int oct = 0; oct < 4; ++oct)
            acc2[mt][oct] = (f32x4){0.f, 0.f, 0.f, 0.f};

    const i32x4* aPk = (const i32x4*)h1p;
    const int abase = (mbase * 16 + lr) * 17 + lg * 2;   // i32x4 units
    const i32x4* w2f = (const i32x4*)wfrag2;
    #pragma unroll
    for (int dk = 0; dk < 5; ++dk) {
        #pragma unroll
        for (int ks = 0; ks < 2; ++ks) {
            Frag bh[4], bl[4];
            #pragma unroll
            for (int oct = 0; oct < 4; ++oct) {
                bh[oct].q = w2f[((dk * 2 + ks) * 8 + nbase + oct) * 64 + lane];
                bl[oct].q = w2f[(((5 + dk) * 2 + ks) * 8 + nbase + oct) * 64 + lane];
            }
            #pragma unroll
            for (int mt = 0; mt < 3; ++mt) {
                const int idx = abase + mt * 272 + dk * 17 + ks * 8;
                const i32x4 q0 = aPk[idx], q1 = aPk[idx + 1];
                unsigned p[8];
                #pragma unroll
                for (int e = 0; e < 4; ++e) { p[e] = q0[e]; p[4 + e] = q1[e]; }
                Frag ah, al;
                #pragma unroll
                for (int wj = 0; wj < 4; ++wj) {
                    ah.u[wj] = __builtin_amdgcn_perm(p[2*wj+1], p[2*wj], 0x07060302u);
                    al.u[wj] = __builtin_amdgcn_perm(p[2*wj+1], p[2*wj], 0x05040100u);
                }
                #pragma unroll
                for (int oct = 0; oct < 4; ++oct)
                    acc2[mt][oct] = __builtin_amdgcn_mfma_f32_16x16x32_bf16(ah.v, bh[oct].v, acc2[mt][oct], 0, 0, 0);
                #pragma unroll
                for (int oct = 0; oct < 4; ++oct)
                    acc2[mt][oct] = __builtin_amdgcn_mfma_f32_16x16x32_bf16(ah.v, bl[oct].v, acc2[mt][oct], 0, 0, 0);
                #pragma unroll
                for (int oct = 0; oct < 4; ++oct)
                    acc2[mt][oct] = __builtin_amdgcn_mfma_f32_16x16x32_bf16(al.v, bh[oct].v, acc2[mt][oct], 0, 0, 0);
            }
        }
    }

    // ---- epilogue: bias+relu+pool4 + fc7 dots ----
    float dot[7] = {0.f, 0.f, 0.f, 0.f, 0.f, 0.f, 0.f};
    {
        float b2v[4];
        #pragma unroll
        for (int oct = 0; oct < 4; ++oct) b2v[oct] = b2[(nbase + oct) * 16 + lr];
        #pragma unroll
        for (int mt = 0; mt < 3; ++mt) {
            const int q = (mbase + mt) * 4 + lg;
            #pragma unroll
            for (int oct = 0; oct < 4; ++oct) {
                float s = 0.f;
                #pragma unroll
                for (int r4 = 0; r4 < 4; ++r4)
                    s += fmaxf(acc2[mt][oct][r4] + b2v[oct], 0.f);
                s *= 0.25f;
                const int idx = ((nbase + oct) * 16 + lr) * 24 + q;
                const f32x4* fp = (const f32x4*)(fc7 + idx * 8);
                const f32x4 f0 = fp[0], f1 = fp[1];
                dot[0] += s * f0[0]; dot[1] += s * f0[1];
                dot[2] += s * f0[2]; dot[3] += s * f0[3];
                dot[4] += s * f1[0]; dot[5] += s * f1[1];
                dot[6] += s * f1[2];
            }
        }
    }

    #pragma unroll
    for (int j = 0; j < 7; ++j) {
        float s = dot[j];
        #pragma unroll
        for (int off = 32; off; off >>= 1) s += __shfl_down(s, off);
        if (lane == 0) red[w * 8 + j] = s;
    }
    __syncthreads();
    if (t < 7) {
        float s = red[t] + red[8 + t] + red[16 + t] + red[24 + t];
        s += (t < 6) ? fc_b[t] : taubp[0];
        params[(size_t)b * 8 + t] = s;
    }
}

// ---------------------------------------------------------------------------
// Kernel 2: DMP rollout — 1 thread per batch element.
// ---------------------------------------------------------------------------
__global__ void rollout_kernel(const float* __restrict__ params,
                               const float* __restrict__ y0,
                               float* __restrict__ out) {
    const int b = blockIdx.x * 256 + threadIdx.x;
    const float* p = params + (size_t)b * 8;
    const float goal = p[0];
    const float w0 = p[1], w1 = p[2], w2 = p[3], w3 = p[4], w4 = p[5];
    const float tau = p[6];
    const float y0v = y0[b];

    const float c0 = 1.0f;
    const float c1 = 0.77880078307140486825f;
    const float c2 = 0.60653065971263342360f;
    const float c3 = 0.47236655274101470714f;
    const float c4 = 0.36787944117144232160f;
    const float inv2s = -0.5f / 11.180339887498949f;
    const float e0 = inv2s * c0, e1 = inv2s * c1, e2 = inv2s * c2,
                e3 = inv2s * c3, e4 = inv2s * c4;

    float x = 1.0f, y = y0v, z = 0.01f * tau;
    const float td = tau * 0.01f;
    const float gmy0 = goal - y0v;
    float* ob = out + (size_t)b * 101;
    ob[0] = y0v;
    for (int s = 1; s <= 100; ++s) {
        x = x - x * td;
        const float d0 = x - c0, d1 = x - c1, d2 = x - c2, d3 = x - c3, d4 = x - c4;
        const float p0 = __expf(e0 * d0 * d0);
        const float p1 = __expf(e1 * d1 * d1);
        const float p2 = __expf(e2 * d2 * d2);
        const float p3 = __expf(e3 * d3 * d3);
        const float p4 = __expf(e4 * d4 * d4);
        const float den = p0 + p1 + p2 + p3 + p4;
        const float num = w0 * p0 + w1 * p1 + w2 * p2 + w3 * p3 + w4 * p4;
        const float fx = (num / den) * x * gmy0;
        const float dz = 25.0f * (6.25f * (goal - y) - z) + fx;
        const float dy = z;
        y += dy * td;
        z += dz * td;
        ob[s] = y;
    }
}

extern "C" void kernel_launch(void* const* d_in, const int* in_sizes, int n_in,
                              void* d_out, int out_size, void* d_ws, size_t ws_size,
                              hipStream_t stream) {
    const float* input = (const float*)d_in[0];
    const float* y0    = (const float*)d_in[1];
    const float* w1    = (const float*)d_in[2];
    const float* b1    = (const float*)d_in[3];
    const float* w2    = (const float*)d_in[4];
    const float* b2    = (const float*)d_in[5];
    const float* fc_w  = (const float*)d_in[6];
    const float* fc_b  = (const float*)d_in[7];
    const float* L_w   = (const float*)d_in[8];
    const float* L_b   = (const float*)d_in[9];
    float* out = (float*)d_out;

    float* ws      = (float*)d_ws;
    float* fc7     = ws;                          // 24576 f
    float* taub    = ws + 24576;                  // pad to 64
    float* params  = ws + 24640;                  // 32768 f
    unsigned* wfrag1 = (unsigned*)(ws + 57408);   // 4096 u32
    unsigned* wfrag2 = wfrag1 + 4096;             // 40960 u32

    const int B = in_sizes[1];                    // 4096

    precompute_fc<<<12, 1024, 0, stream>>>(fc_w, L_w, fc7);
    precompute_frags<<<21, 256, 0, stream>>>(w1, w2, fc_b, L_w, L_b,
                                             taub, wfrag1, wfrag2);
    fused_kernel<<<B, 256, 0, stream>>>(input, b1, b2, wfrag1, wfrag2,
                                        fc7, fc_b, taub, params);
    rollout_kernel<<<B / 256, 256, 0, stream>>>(params, y0, out);
}

// Round 6
// 163.522 us; speedup vs baseline: 1.1206x; 1.1206x over previous
//
#include <hip/hip_runtime.h>
#include <math.h>

// ---------------------------------------------------------------------------
// B=4096. conv1 (64,5,7) pad3 + relu + pool4 -> h1 (64,96)
//         conv2 (128,64,5) pad2 + relu + pool4 -> feat (128,24)
//         fc: only cols 0..5 of (404,3072) + tau = feat·(L_w@fc_w) + const.
// Split-bf16 MFMA (hi+lo, 3 mfma/product — REQUIRED precision: rollout
// amplifies param error ~1e6x). conv2 = 5 shifted GEMMs over K=64(ic).
// R6: hi/lo weight frags adjacent (1 addr, 2 b128), conv2 wave-split
// 6mt x 2oct (half the per-wave B VMEM, batch-issued), conv1 B hoisted.
// C/D layout (m89): col=lane&15 -> oc, row=(lane>>4)*4+reg -> pos.
// ---------------------------------------------------------------------------

typedef short bf16x8 __attribute__((ext_vector_type(8)));
typedef float f32x4  __attribute__((ext_vector_type(4)));
typedef int   i32x4  __attribute__((ext_vector_type(4)));

union Frag { int u[4]; i32x4 q; bf16x8 v; };

__device__ __forceinline__ unsigned bf16_rne(float f) {
    unsigned u = __float_as_uint(f);
    return (u + 0x7fffu + ((u >> 16) & 1u)) >> 16;
}
__device__ __forceinline__ unsigned packsplit(float f) {
    unsigned hi = bf16_rne(f);
    float lo = f - __uint_as_float(hi << 16);
    return (hi << 16) | bf16_rne(lo);
}

// ---------------------------------------------------------------------------
// Kernel 0a: fc7 table. 12 blocks x 1024 threads; j-loop split 4 ways.
// ---------------------------------------------------------------------------
__global__ void precompute_fc(const float* __restrict__ fc_w,
                              const float* __restrict__ L_w,
                              float* __restrict__ fc7) {
    __shared__ float part[3][256];
    const int t = threadIdx.x, k = blockIdx.x * 256 + (t & 255), jc = t >> 8;
    const int j0 = jc * 101;
    float s = 0.f;
    #pragma unroll 4
    for (int j = j0; j < j0 + 101; ++j) s += L_w[j] * fc_w[j * 3072 + k];
    if (jc) part[jc - 1][t & 255] = s;
    __syncthreads();
    if (jc == 0) {
        const int kk = t & 255;
        float r[8];
        #pragma unroll
        for (int j = 0; j < 6; ++j) r[j] = fc_w[j * 3072 + k];
        r[6] = s + part[0][kk] + part[1][kk] + part[2][kk];
        r[7] = 0.f;
        #pragma unroll
        for (int j = 0; j < 8; ++j) fc7[k * 8 + j] = r[j];
    }
}

// ---------------------------------------------------------------------------
// Kernel 0b: taub + weight-fragment tables, hi/lo ADJACENT per lane.
//  wfrag1: [ks2][oct4][lane64][part2][4u32]        (conv1, K'=64 padded)
//  wfrag2: [dk5][ks2][oct8][lane64][part2][4u32]   (conv2 taps, K=64=ic)
// ---------------------------------------------------------------------------
__global__ void precompute_frags(const float* __restrict__ w1,
                                 const float* __restrict__ w2,
                                 const float* __restrict__ fc_b,
                                 const float* __restrict__ L_w,
                                 const float* __restrict__ L_b,
                                 float* __restrict__ taub,
                                 unsigned* __restrict__ wfrag1,
                                 unsigned* __restrict__ wfrag2) {
    const int t = threadIdx.x, bb = blockIdx.x;
    if (bb == 0) {
        if (t < 64) {
            float s = 0.f;
            for (int j = t; j < 404; j += 64) s += L_w[j] * fc_b[j];
            #pragma unroll
            for (int off = 32; off; off >>= 1) s += __shfl_down(s, off);
            if (t == 0) taub[0] = s + L_b[0];
        }
        for (int it = t; it < 1024; it += 256) {    // conv1 frags
            const int part = it & 1, lane = (it >> 1) & 63,
                      oct = (it >> 7) & 3, ks = it >> 9;
            const int oc = oct * 16 + (lane & 15);
            unsigned h[8];
            #pragma unroll
            for (int j = 0; j < 8; ++j) {
                const int kp = ks * 32 + (lane >> 4) * 8 + j;  // k' = dk*8+ic
                const int dk = kp >> 3, ic = kp & 7;
                float v = (ic < 5 && dk < 7) ? w1[oc * 35 + ic * 7 + dk] : 0.f;
                unsigned hb = bf16_rne(v);
                if (part) hb = bf16_rne(v - __uint_as_float(hb << 16));
                h[j] = hb;
            }
            #pragma unroll
            for (int wj = 0; wj < 4; ++wj)
                wfrag1[it * 4 + wj] = (h[2 * wj + 1] << 16) | h[2 * wj];
        }
    } else {                                        // conv2 tap frags: 10240
        const int base = (bb - 1) * 512;
        #pragma unroll
        for (int r = 0; r < 2; ++r) {
            const int it = base + r * 256 + t;
            const int part = it & 1, lane = (it >> 1) & 63,
                      oct = (it >> 7) & 7, step = it >> 10;   // step = dk*2+ks
            const int oc = oct * 16 + (lane & 15);
            const int dk = step >> 1, ks = step & 1;
            unsigned h[8];
            #pragma unroll
            for (int j = 0; j < 8; ++j) {
                const int ic = ks * 32 + (lane >> 4) * 8 + j;   // k = ic
                const float v = w2[oc * 320 + ic * 5 + dk];
                unsigned hb = bf16_rne(v);
                if (part) hb = bf16_rne(v - __uint_as_float(hb << 16));
                h[j] = hb;
            }
            #pragma unroll
            for (int wj = 0; wj < 4; ++wj)
                wfrag2[it * 4 + wj] = (h[2 * wj + 1] << 16) | h[2 * wj];
        }
    }
}

// ---------------------------------------------------------------------------
// Kernel 1: fused conv1+conv2+fc, one batch per block, 4 blocks/CU.
// LDS (36736 B): lds_in u32[6][392] (row5=zeros), h1p u32[100][68] packed
// hi|lo (rows 0,1,98,99 halo-zero), red f32[32].
// ---------------------------------------------------------------------------
__global__ __launch_bounds__(256, 4) void fused_kernel(
    const float* __restrict__ input,
    const float* __restrict__ b1,
    const float* __restrict__ b2,
    const unsigned* __restrict__ wfrag1,
    const unsigned* __restrict__ wfrag2,
    const float* __restrict__ fc7,
    const float* __restrict__ fc_b,
    const float* __restrict__ taubp,
    float* __restrict__ params)
{
    __shared__ unsigned lds_in[2352];
    __shared__ unsigned h1p[6800];
    __shared__ float red[32];

    const int t = threadIdx.x, b = blockIdx.x;
    const int lane = t & 63, w = t >> 6;
    const int lg = lane >> 4, lr = lane & 15;

    // ---- zero lds_in + h1p halo rows (0,1,98,99) ----
    for (int i = t; i < 2352; i += 256) lds_in[i] = 0u;
    for (int i = t; i < 272; i += 256) {
        const int r = i / 68, wd = i - r * 68;
        const int row = (r < 2) ? r : 96 + r;
        h1p[row * 68 + wd] = 0u;
    }
    __syncthreads();
    const float* inb = input + (size_t)b * 1920;
    for (int i = t; i < 1920; i += 256) {
        const int ic = i / 384, x = i - ic * 384;
        lds_in[ic * 392 + 3 + x] = packsplit(inb[i]);
    }
    __syncthreads();

    // ---------------- conv1: C[pos=384][oc=64], K'=64 ----------------
    // B-frags hoisted: [ks][part][oct] = 16 frags (64 regs), loaded once.
    const i32x4* w1f = (const i32x4*)wfrag1;
    Frag c1b[2][2][4];
    #pragma unroll
    for (int ks = 0; ks < 2; ++ks)
        #pragma unroll
        for (int oct = 0; oct < 4; ++oct) {
            const int fi = ((ks * 4 + oct) * 64 + lane) * 2;
            c1b[ks][0][oct].q = w1f[fi];
            c1b[ks][1][oct].q = w1f[fi + 1];
        }
    float b1v[4];
    #pragma unroll
    for (int oct = 0; oct < 4; ++oct) b1v[oct] = b1[oct * 16 + lr];

    const unsigned* aB1 = lds_in + w * 96 + lr + lg;
    #pragma unroll
    for (int mt = 0; mt < 6; ++mt) {
        f32x4 acc[4];
        #pragma unroll
        for (int oct = 0; oct < 4; ++oct) acc[oct] = (f32x4){0.f, 0.f, 0.f, 0.f};
        #pragma unroll
        for (int ks = 0; ks < 2; ++ks) {
            unsigned p[8];
            #pragma unroll
            for (int j = 0; j < 8; ++j) {
                const int jr = (j < 5) ? j : 5;           // row5 = zeros
                p[j] = aB1[mt * 16 + ks * 4 + jr * 392];
            }
            Frag ah, al;
            #pragma unroll
            for (int wj = 0; wj < 4; ++wj) {
                ah.u[wj] = __builtin_amdgcn_perm(p[2*wj+1], p[2*wj], 0x07060302u);
                al.u[wj] = __builtin_amdgcn_perm(p[2*wj+1], p[2*wj], 0x05040100u);
            }
            #pragma unroll
            for (int oct = 0; oct < 4; ++oct)
                acc[oct] = __builtin_amdgcn_mfma_f32_16x16x32_bf16(ah.v, c1b[ks][0][oct].v, acc[oct], 0, 0, 0);
            #pragma unroll
            for (int oct = 0; oct < 4; ++oct)
                acc[oct] = __builtin_amdgcn_mfma_f32_16x16x32_bf16(ah.v, c1b[ks][1][oct].v, acc[oct], 0, 0, 0);
            #pragma unroll
            for (int oct = 0; oct < 4; ++oct)
                acc[oct] = __builtin_amdgcn_mfma_f32_16x16x32_bf16(al.v, c1b[ks][0][oct].v, acc[oct], 0, 0, 0);
        }
        const int c = (w * 6 + mt) * 4 + lg;
        #pragma unroll
        for (int oct = 0; oct < 4; ++oct) {
            float s = 0.f;
            #pragma unroll
            for (int r4 = 0; r4 < 4; ++r4) s += fmaxf(acc[oct][r4] + b1v[oct], 0.f);
            h1p[(c + 2) * 68 + oct * 16 + lr] = packsplit(0.25f * s);
        }
    }
    __syncthreads();

    // -------- conv2: 5 taps x K=64, wave-split 6mt x 2oct --------
    // Per step (dk,ks): batch-load 2 octs' B (4 b128, 2 addrs), then 6 mt
    // { 2 A b128, 8 perms, 2 oct x 3 MFMA }.
    f32x4 acc2[6][2];
    #pragma unroll
    for (int mt = 0; mt < 6; ++mt)
        #pragma unroll
        for (int oct = 0; oct < 2; ++oct)
            acc2[mt][oct] = (f32x4){0.f, 0.f, 0.f, 0.f};

    const i32x4* aPk = (const i32x4*)h1p;
    const int abase = lr * 17 + lg * 2;                  // i32x4 units
    const i32x4* w2f = (const i32x4*)wfrag2;
    #pragma unroll
    for (int dk = 0; dk < 5; ++dk) {
        #pragma unroll
        for (int ks = 0; ks < 2; ++ks) {
            Frag bh[2], bl[2];
            #pragma unroll
            for (int oct = 0; oct < 2; ++oct) {
                const int fi = (((dk * 2 + ks) * 8 + w * 2 + oct) * 64 + lane) * 2;
                bh[oct].q = w2f[fi];
                bl[oct].q = w2f[fi + 1];
            }
            #pragma unroll
            for (int mt = 0; mt < 6; ++mt) {
                const int idx = abase + (mt * 16 + dk) * 17 + ks * 8;
                const i32x4 q0 = aPk[idx], q1 = aPk[idx + 1];
                unsigned p[8];
                #pragma unroll
                for (int e = 0; e < 4; ++e) { p[e] = q0[e]; p[4 + e] = q1[e]; }
                Frag ah, al;
                #pragma unroll
                for (int wj = 0; wj < 4; ++wj) {
                    ah.u[wj] = __builtin_amdgcn_perm(p[2*wj+1], p[2*wj], 0x07060302u);
                    al.u[wj] = __builtin_amdgcn_perm(p[2*wj+1], p[2*wj], 0x05040100u);
                }
                #pragma unroll
                for (int oct = 0; oct < 2; ++oct)
                    acc2[mt][oct] = __builtin_amdgcn_mfma_f32_16x16x32_bf16(ah.v, bh[oct].v, acc2[mt][oct], 0, 0, 0);
                #pragma unroll
                for (int oct = 0; oct < 2; ++oct)
                    acc2[mt][oct] = __builtin_amdgcn_mfma_f32_16x16x32_bf16(ah.v, bl[oct].v, acc2[mt][oct], 0, 0, 0);
                #pragma unroll
                for (int oct = 0; oct < 2; ++oct)
                    acc2[mt][oct] = __builtin_amdgcn_mfma_f32_16x16x32_bf16(al.v, bh[oct].v, acc2[mt][oct], 0, 0, 0);
            }
        }
    }

    // ---- epilogue: bias+relu+pool4 + fc7 dots ----
    float dot[7] = {0.f, 0.f, 0.f, 0.f, 0.f, 0.f, 0.f};
    {
        float b2v[2];
        #pragma unroll
        for (int oct = 0; oct < 2; ++oct) b2v[oct] = b2[(w * 2 + oct) * 16 + lr];
        #pragma unroll
        for (int mt = 0; mt < 6; ++mt) {
            const int q = mt * 4 + lg;
            #pragma unroll
            for (int oct = 0; oct < 2; ++oct) {
                float s = 0.f;
                #pragma unroll
                for (int r4 = 0; r4 < 4; ++r4)
                    s += fmaxf(acc2[mt][oct][r4] + b2v[oct], 0.f);
                s *= 0.25f;
                const int idx = ((w * 2 + oct) * 16 + lr) * 24 + q;
                const f32x4* fp = (const f32x4*)(fc7 + idx * 8);
                const f32x4 f0 = fp[0], f1 = fp[1];
                dot[0] += s * f0[0]; dot[1] += s * f0[1];
                dot[2] += s * f0[2]; dot[3] += s * f0[3];
                dot[4] += s * f1[0]; dot[5] += s * f1[1];
                dot[6] += s * f1[2];
            }
        }
    }

    #pragma unroll
    for (int j = 0; j < 7; ++j) {
        float s = dot[j];
        #pragma unroll
        for (int off = 32; off; off >>= 1) s += __shfl_down(s, off);
        if (lane == 0) red[w * 8 + j] = s;
    }
    __syncthreads();
    if (t < 7) {
        float s = red[t] + red[8 + t] + red[16 + t] + red[24 + t];
        s += (t < 6) ? fc_b[t] : taubp[0];
        params[(size_t)b * 8 + t] = s;
    }
}

// ---------------------------------------------------------------------------
// Kernel 2: DMP rollout — 1 thread per batch element.
// ---------------------------------------------------------------------------
__global__ void rollout_kernel(const float* __restrict__ params,
                               const float* __restrict__ y0,
                               float* __restrict__ out) {
    const int b = blockIdx.x * 256 + threadIdx.x;
    const float* p = params + (size_t)b * 8;
    const float goal = p[0];
    const float w0 = p[1], w1 = p[2], w2 = p[3], w3 = p[4], w4 = p[5];
    const float tau = p[6];
    const float y0v = y0[b];

    const float c0 = 1.0f;
    const float c1 = 0.77880078307140486825f;
    const float c2 = 0.60653065971263342360f;
    const float c3 = 0.47236655274101470714f;
    const float c4 = 0.36787944117144232160f;
    const float inv2s = -0.5f / 11.180339887498949f;
    const float e0 = inv2s * c0, e1 = inv2s * c1, e2 = inv2s * c2,
                e3 = inv2s * c3, e4 = inv2s * c4;

    float x = 1.0f, y = y0v, z = 0.01f * tau;
    const float td = tau * 0.01f;
    const float gmy0 = goal - y0v;
    float* ob = out + (size_t)b * 101;
    ob[0] = y0v;
    for (int s = 1; s <= 100; ++s) {
        x = x - x * td;
        const float d0 = x - c0, d1 = x - c1, d2 = x - c2, d3 = x - c3, d4 = x - c4;
        const float p0 = __expf(e0 * d0 * d0);
        const float p1 = __expf(e1 * d1 * d1);
        const float p2 = __expf(e2 * d2 * d2);
        const float p3 = __expf(e3 * d3 * d3);
        const float p4 = __expf(e4 * d4 * d4);
        const float den = p0 + p1 + p2 + p3 + p4;
        const float num = w0 * p0 + w1 * p1 + w2 * p2 + w3 * p3 + w4 * p4;
        const float fx = (num / den) * x * gmy0;
        const float dz = 25.0f * (6.25f * (goal - y) - z) + fx;
        const float dy = z;
        y += dy * td;
        z += dz * td;
        ob[s] = y;
    }
}

extern "C" void kernel_launch(void* const* d_in, const int* in_sizes, int n_in,
                              void* d_out, int out_size, void* d_ws, size_t ws_size,
                              hipStream_t stream) {
    const float* input = (const float*)d_in[0];
    const float* y0    = (const float*)d_in[1];
    const float* w1    = (const float*)d_in[2];
    const float* b1    = (const float*)d_in[3];
    const float* w2    = (const float*)d_in[4];
    const float* b2    = (const float*)d_in[5];
    const float* fc_w  = (const float*)d_in[6];
    const float* fc_b  = (const float*)d_in[7];
    const float* L_w   = (const float*)d_in[8];
    const float* L_b   = (const float*)d_in[9];
    float* out = (float*)d_out;

    float* ws      = (float*)d_ws;
    float* fc7     = ws;                          // 24576 f
    float* taub    = ws + 24576;                  // pad to 64
    float* params  = ws + 24640;                  // 32768 f
    unsigned* wfrag1 = (unsigned*)(ws + 57408);   // 4096 u32
    unsigned* wfrag2 = wfrag1 + 4096;             // 40960 u32

    const int B = in_sizes[1];                    // 4096

    precompute_fc<<<12, 1024, 0, stream>>>(fc_w, L_w, fc7);
    precompute_frags<<<21, 256, 0, stream>>>(w1, w2, fc_b, L_w, L_b,
                                             taub, wfrag1, wfrag2);
    fused_kernel<<<B, 256, 0, stream>>>(input, b1, b2, wfrag1, wfrag2,
                                        fc7, fc_b, taub, params);
    rollout_kernel<<<B / 256, 256, 0, stream>>>(params, y0, out);
}

// Round 7
// 156.616 us; speedup vs baseline: 1.1700x; 1.0441x over previous
//
#include <hip/hip_runtime.h>
#include <math.h>

// ---------------------------------------------------------------------------
// B=4096. conv1 (64,5,7) pad3 + relu + pool4 -> h1 (64,96)
//         conv2 (128,64,5) pad2 + relu + pool4 -> feat (128,24)
//         fc: only cols 0..5 of (404,3072) + tau = feat·(L_w@fc_w) + const.
// Split-bf16 MFMA (hi+lo, 3 mfma/product — REQUIRED precision: rollout
// amplifies param error ~1e6x). conv2 = 5 shifted GEMMs over K=64(ic).
// R7: h1 in SEPARATE hi/lo bf16[100][72] arrays -> A-frag = direct
// ds_read_b128, no v_perm; manual distance-1 double-buffered pipeline for
// A (LDS) and B (global) so MFMA bursts cover load latency.
// C/D layout (m89): col=lane&15 -> oc, row=(lane>>4)*4+reg -> pos.
// ---------------------------------------------------------------------------

typedef short bf16x8 __attribute__((ext_vector_type(8)));
typedef float f32x4  __attribute__((ext_vector_type(4)));
typedef int   i32x4  __attribute__((ext_vector_type(4)));

union Frag { int u[4]; i32x4 q; bf16x8 v; };

__device__ __forceinline__ unsigned bf16_rne(float f) {
    unsigned u = __float_as_uint(f);
    return (u + 0x7fffu + ((u >> 16) & 1u)) >> 16;
}
__device__ __forceinline__ unsigned packsplit(float f) {
    unsigned hi = bf16_rne(f);
    float lo = f - __uint_as_float(hi << 16);
    return (hi << 16) | bf16_rne(lo);
}

// ---------------------------------------------------------------------------
// Kernel 0 (merged): fc7 (blocks 0..47), taub+wfrag1 (48), wfrag2 (49..68).
//  wfrag1: [ks2][oct4][lane64][part2][4u32]        (conv1, K'=64 padded)
//  wfrag2: [dk5][ks2][oct8][lane64][part2][4u32]   (conv2 taps, K=64=ic)
// ---------------------------------------------------------------------------
__global__ void precompute_kernel(const float* __restrict__ w1,
                                  const float* __restrict__ w2,
                                  const float* __restrict__ fc_w,
                                  const float* __restrict__ fc_b,
                                  const float* __restrict__ L_w,
                                  const float* __restrict__ L_b,
                                  float* __restrict__ fc7,
                                  float* __restrict__ taub,
                                  unsigned* __restrict__ wfrag1,
                                  unsigned* __restrict__ wfrag2) {
    const int t = threadIdx.x, bb = blockIdx.x;
    if (bb < 48) {
        __shared__ float part[3][64];
        const int k = bb * 64 + (t & 63), jc = t >> 6;
        const int j0 = jc * 101;
        float s = 0.f;
        #pragma unroll 4
        for (int j = j0; j < j0 + 101; ++j) s += L_w[j] * fc_w[j * 3072 + k];
        if (jc) part[jc - 1][t & 63] = s;
        __syncthreads();
        if (jc == 0) {
            const int kk = t & 63;
            float r[8];
            #pragma unroll
            for (int j = 0; j < 6; ++j) r[j] = fc_w[j * 3072 + k];
            r[6] = s + part[0][kk] + part[1][kk] + part[2][kk];
            r[7] = 0.f;
            #pragma unroll
            for (int j = 0; j < 8; ++j) fc7[k * 8 + j] = r[j];
        }
    } else if (bb == 48) {
        if (t < 64) {
            float s = 0.f;
            for (int j = t; j < 404; j += 64) s += L_w[j] * fc_b[j];
            #pragma unroll
            for (int off = 32; off; off >>= 1) s += __shfl_down(s, off);
            if (t == 0) taub[0] = s + L_b[0];
        }
        for (int it = t; it < 1024; it += 256) {    // conv1 frags
            const int part = it & 1, lane = (it >> 1) & 63,
                      oct = (it >> 7) & 3, ks = it >> 9;
            const int oc = oct * 16 + (lane & 15);
            unsigned h[8];
            #pragma unroll
            for (int j = 0; j < 8; ++j) {
                const int kp = ks * 32 + (lane >> 4) * 8 + j;  // k' = dk*8+ic
                const int dk = kp >> 3, ic = kp & 7;
                float v = (ic < 5 && dk < 7) ? w1[oc * 35 + ic * 7 + dk] : 0.f;
                unsigned hb = bf16_rne(v);
                if (part) hb = bf16_rne(v - __uint_as_float(hb << 16));
                h[j] = hb;
            }
            #pragma unroll
            for (int wj = 0; wj < 4; ++wj)
                wfrag1[it * 4 + wj] = (h[2 * wj + 1] << 16) | h[2 * wj];
        }
    } else {                                        // conv2 tap frags: 10240
        const int base = (bb - 49) * 512;
        #pragma unroll
        for (int r = 0; r < 2; ++r) {
            const int it = base + r * 256 + t;
            const int part = it & 1, lane = (it >> 1) & 63,
                      oct = (it >> 7) & 7, step = it >> 10;   // step = dk*2+ks
            const int oc = oct * 16 + (lane & 15);
            const int dk = step >> 1, ks = step & 1;
            unsigned h[8];
            #pragma unroll
            for (int j = 0; j < 8; ++j) {
                const int ic = ks * 32 + (lane >> 4) * 8 + j;   // k = ic
                const float v = w2[oc * 320 + ic * 5 + dk];
                unsigned hb = bf16_rne(v);
                if (part) hb = bf16_rne(v - __uint_as_float(hb << 16));
                h[j] = hb;
            }
            #pragma unroll
            for (int wj = 0; wj < 4; ++wj)
                wfrag2[it * 4 + wj] = (h[2 * wj + 1] << 16) | h[2 * wj];
        }
    }
}

// ---------------------------------------------------------------------------
// Kernel 1: fused conv1+conv2+fc, one batch per block.
// LDS (38336 B): lds_in u32[6][392] packed (row5=zeros),
//   h1_hi/h1_lo bf16[100][72] (rows 0,1,98,99 halo-zero), red f32[32].
// ---------------------------------------------------------------------------
__global__ __launch_bounds__(256, 3) void fused_kernel(
    const float* __restrict__ input,
    const float* __restrict__ b1,
    const float* __restrict__ b2,
    const unsigned* __restrict__ wfrag1,
    const unsigned* __restrict__ wfrag2,
    const float* __restrict__ fc7,
    const float* __restrict__ fc_b,
    const float* __restrict__ taubp,
    float* __restrict__ params)
{
    __shared__ unsigned lds_in[2352];
    __shared__ __align__(16) unsigned short h1_hi[7200];   // [100][72]
    __shared__ __align__(16) unsigned short h1_lo[7200];
    __shared__ float red[32];

    const int t = threadIdx.x, b = blockIdx.x;
    const int lane = t & 63, w = t >> 6;
    const int lg = lane >> 4, lr = lane & 15;

    // ---- zero lds_in + h1 halo rows (0,1,98,99) in both arrays ----
    for (int i = t; i < 2352; i += 256) lds_in[i] = 0u;
    if (t < 144) {
        const int r = t / 36, wd = t - r * 36;
        const int row = (r < 2) ? r : 96 + r;
        ((unsigned*)h1_hi)[row * 36 + wd] = 0u;
        ((unsigned*)h1_lo)[row * 36 + wd] = 0u;
    }
    __syncthreads();
    const float* inb = input + (size_t)b * 1920;
    for (int i = t; i < 1920; i += 256) {
        const int ic = i / 384, x = i - ic * 384;
        lds_in[ic * 392 + 3 + x] = packsplit(inb[i]);
    }
    __syncthreads();

    // ---------------- conv1: C[pos=384][oc=64], K'=64 ----------------
    // B hoisted: [ks][part][oct] (64 VGPR); A packed+perm, distance-1 pipe.
    const i32x4* w1f = (const i32x4*)wfrag1;
    Frag c1b[2][2][4];
    #pragma unroll
    for (int ks = 0; ks < 2; ++ks)
        #pragma unroll
        for (int oct = 0; oct < 4; ++oct) {
            const int fi = ((ks * 4 + oct) * 64 + lane) * 2;
            c1b[ks][0][oct].q = w1f[fi];
            c1b[ks][1][oct].q = w1f[fi + 1];
        }
    float b1v[4];
    #pragma unroll
    for (int oct = 0; oct < 4; ++oct) b1v[oct] = b1[oct * 16 + lr];

    const unsigned* aB1 = lds_in + w * 96 + lr + lg;
    unsigned pbuf[2][8];
    #pragma unroll
    for (int j = 0; j < 8; ++j) {
        const int jr = (j < 5) ? j : 5;               // rows 5..7 = zero row
        pbuf[0][j] = aB1[jr * 392];                   // (mt0,ks0)
    }
    #pragma unroll
    for (int mt = 0; mt < 6; ++mt) {
        f32x4 acc[4];
        #pragma unroll
        for (int oct = 0; oct < 4; ++oct) acc[oct] = (f32x4){0.f, 0.f, 0.f, 0.f};
        #pragma unroll
        for (int ks = 0; ks < 2; ++ks) {
            const int it = mt * 2 + ks, cur = it & 1, nxt = cur ^ 1;
            if (it < 11) {
                const int nit = it + 1, nmt = nit >> 1, nks = nit & 1;
                #pragma unroll
                for (int j = 0; j < 8; ++j) {
                    const int jr = (j < 5) ? j : 5;
                    pbuf[nxt][j] = aB1[nmt * 16 + nks * 4 + jr * 392];
                }
            }
            Frag ah, al;
            #pragma unroll
            for (int wj = 0; wj < 4; ++wj) {
                ah.u[wj] = __builtin_amdgcn_perm(pbuf[cur][2*wj+1], pbuf[cur][2*wj], 0x07060302u);
                al.u[wj] = __builtin_amdgcn_perm(pbuf[cur][2*wj+1], pbuf[cur][2*wj], 0x05040100u);
            }
            #pragma unroll
            for (int oct = 0; oct < 4; ++oct)
                acc[oct] = __builtin_amdgcn_mfma_f32_16x16x32_bf16(ah.v, c1b[ks][0][oct].v, acc[oct], 0, 0, 0);
            #pragma unroll
            for (int oct = 0; oct < 4; ++oct)
                acc[oct] = __builtin_amdgcn_mfma_f32_16x16x32_bf16(ah.v, c1b[ks][1][oct].v, acc[oct], 0, 0, 0);
            #pragma unroll
            for (int oct = 0; oct < 4; ++oct)
                acc[oct] = __builtin_amdgcn_mfma_f32_16x16x32_bf16(al.v, c1b[ks][0][oct].v, acc[oct], 0, 0, 0);
        }
        const int c = (w * 6 + mt) * 4 + lg;
        #pragma unroll
        for (int oct = 0; oct < 4; ++oct) {
            float s = 0.f;
            #pragma unroll
            for (int r4 = 0; r4 < 4; ++r4) s += fmaxf(acc[oct][r4] + b1v[oct], 0.f);
            const float v = 0.25f * s;
            const unsigned hi = bf16_rne(v);
            const unsigned lo = bf16_rne(v - __uint_as_float(hi << 16));
            const int idx = (c + 2) * 72 + oct * 16 + lr;
            h1_hi[idx] = (unsigned short)hi;
            h1_lo[idx] = (unsigned short)lo;
        }
    }
    __syncthreads();

    // -------- conv2: 5 taps x K=64, wave-split 6mt x 2oct, pipelined ------
    f32x4 acc2[6][2];
    #pragma unroll
    for (int mt = 0; mt < 6; ++mt)
        #pragma unroll
        for (int oct = 0; oct < 2; ++oct)
            acc2[mt][oct] = (f32x4){0.f, 0.f, 0.f, 0.f};

    const int a_base = lr * 72 + lg * 8;              // element offset
    const i32x4* w2f = (const i32x4*)wfrag2;
    Frag bh[2][2], bl[2][2];                          // [buf][oct]
    Frag ah2[2], al2[2];

    // prologue: B(step0), A(mt0, step0)
    #pragma unroll
    for (int oct = 0; oct < 2; ++oct) {
        const int fi = ((w * 2 + oct) * 64 + lane) * 2;
        bh[0][oct].q = w2f[fi];
        bl[0][oct].q = w2f[fi + 1];
    }
    ah2[0].q = *(const i32x4*)(h1_hi + a_base);
    al2[0].q = *(const i32x4*)(h1_lo + a_base);

    #pragma unroll
    for (int s = 0; s < 10; ++s) {
        const int dk = s >> 1, ks = s & 1, sb = s & 1, snb = sb ^ 1;
        if (s < 9) {   // issue next step's B global loads now
            #pragma unroll
            for (int oct = 0; oct < 2; ++oct) {
                const int fi = (((s + 1) * 8 + w * 2 + oct) * 64 + lane) * 2;
                bh[snb][oct].q = w2f[fi];
                bl[snb][oct].q = w2f[fi + 1];
            }
        }
        #pragma unroll
        for (int mt = 0; mt < 6; ++mt) {
            const int it = s * 6 + mt, cur = it & 1, nxt = cur ^ 1;
            if (mt < 5) {
                const int eo = a_base + ((mt + 1) * 16 + dk) * 72 + ks * 32;
                ah2[nxt].q = *(const i32x4*)(h1_hi + eo);
                al2[nxt].q = *(const i32x4*)(h1_lo + eo);
            } else if (s < 9) {
                const int eo = a_base + ((s + 1) >> 1) * 72 + ((s + 1) & 1) * 32;
                ah2[nxt].q = *(const i32x4*)(h1_hi + eo);
                al2[nxt].q = *(const i32x4*)(h1_lo + eo);
            }
            acc2[mt][0] = __builtin_amdgcn_mfma_f32_16x16x32_bf16(ah2[cur].v, bh[sb][0].v, acc2[mt][0], 0, 0, 0);
            acc2[mt][1] = __builtin_amdgcn_mfma_f32_16x16x32_bf16(ah2[cur].v, bh[sb][1].v, acc2[mt][1], 0, 0, 0);
            acc2[mt][0] = __builtin_amdgcn_mfma_f32_16x16x32_bf16(ah2[cur].v, bl[sb][0].v, acc2[mt][0], 0, 0, 0);
            acc2[mt][1] = __builtin_amdgcn_mfma_f32_16x16x32_bf16(ah2[cur].v, bl[sb][1].v, acc2[mt][1], 0, 0, 0);
            acc2[mt][0] = __builtin_amdgcn_mfma_f32_16x16x32_bf16(al2[cur].v, bh[sb][0].v, acc2[mt][0], 0, 0, 0);
            acc2[mt][1] = __builtin_amdgcn_mfma_f32_16x16x32_bf16(al2[cur].v, bh[sb][1].v, acc2[mt][1], 0, 0, 0);
        }
    }

    // ---- epilogue: bias+relu+pool4 + fc7 dots ----
    float dot[7] = {0.f, 0.f, 0.f, 0.f, 0.f, 0.f, 0.f};
    {
        float b2v[2];
        #pragma unroll
        for (int oct = 0; oct < 2; ++oct) b2v[oct] = b2[(w * 2 + oct) * 16 + lr];
        #pragma unroll
        for (int mt = 0; mt < 6; ++mt) {
            const int q = mt * 4 + lg;
            #pragma unroll
            for (int oct = 0; oct < 2; ++oct) {
                float s = 0.f;
                #pragma unroll
                for (int r4 = 0; r4 < 4; ++r4)
                    s += fmaxf(acc2[mt][oct][r4] + b2v[oct], 0.f);
                s *= 0.25f;
                const int idx = ((w * 2 + oct) * 16 + lr) * 24 + q;
                const f32x4* fp = (const f32x4*)(fc7 + idx * 8);
                const f32x4 f0 = fp[0], f1 = fp[1];
                dot[0] += s * f0[0]; dot[1] += s * f0[1];
                dot[2] += s * f0[2]; dot[3] += s * f0[3];
                dot[4] += s * f1[0]; dot[5] += s * f1[1];
                dot[6] += s * f1[2];
            }
        }
    }

    #pragma unroll
    for (int j = 0; j < 7; ++j) {
        float s = dot[j];
        #pragma unroll
        for (int off = 32; off; off >>= 1) s += __shfl_down(s, off);
        if (lane == 0) red[w * 8 + j] = s;
    }
    __syncthreads();
    if (t < 7) {
        float s = red[t] + red[8 + t] + red[16 + t] + red[24 + t];
        s += (t < 6) ? fc_b[t] : taubp[0];
        params[(size_t)b * 8 + t] = s;
    }
}

// ---------------------------------------------------------------------------
// Kernel 2: DMP rollout — 1 thread per batch element.
// ---------------------------------------------------------------------------
__global__ void rollout_kernel(const float* __restrict__ params,
                               const float* __restrict__ y0,
                               float* __restrict__ out) {
    const int b = blockIdx.x * 256 + threadIdx.x;
    const float* p = params + (size_t)b * 8;
    const float goal = p[0];
    const float w0 = p[1], w1 = p[2], w2 = p[3], w3 = p[4], w4 = p[5];
    const float tau = p[6];
    const float y0v = y0[b];

    const float c0 = 1.0f;
    const float c1 = 0.77880078307140486825f;
    const float c2 = 0.60653065971263342360f;
    const float c3 = 0.47236655274101470714f;
    const float c4 = 0.36787944117144232160f;
    const float inv2s = -0.5f / 11.180339887498949f;
    const float e0 = inv2s * c0, e1 = inv2s * c1, e2 = inv2s * c2,
                e3 = inv2s * c3, e4 = inv2s * c4;

    float x = 1.0f, y = y0v, z = 0.01f * tau;
    const float td = tau * 0.01f;
    const float gmy0 = goal - y0v;
    float* ob = out + (size_t)b * 101;
    ob[0] = y0v;
    for (int s = 1; s <= 100; ++s) {
        x = x - x * td;
        const float d0 = x - c0, d1 = x - c1, d2 = x - c2, d3 = x - c3, d4 = x - c4;
        const float p0 = __expf(e0 * d0 * d0);
        const float p1 = __expf(e1 * d1 * d1);
        const float p2 = __expf(e2 * d2 * d2);
        const float p3 = __expf(e3 * d3 * d3);
        const float p4 = __expf(e4 * d4 * d4);
        const float den = p0 + p1 + p2 + p3 + p4;
        const float num = w0 * p0 + w1 * p1 + w2 * p2 + w3 * p3 + w4 * p4;
        const float fx = (num / den) * x * gmy0;
        const float dz = 25.0f * (6.25f * (goal - y) - z) + fx;
        const float dy = z;
        y += dy * td;
        z += dz * td;
        ob[s] = y;
    }
}

extern "C" void kernel_launch(void* const* d_in, const int* in_sizes, int n_in,
                              void* d_out, int out_size, void* d_ws, size_t ws_size,
                              hipStream_t stream) {
    const float* input = (const float*)d_in[0];
    const float* y0    = (const float*)d_in[1];
    const float* w1    = (const float*)d_in[2];
    const float* b1    = (const float*)d_in[3];
    const float* w2    = (const float*)d_in[4];
    const float* b2    = (const float*)d_in[5];
    const float* fc_w  = (const float*)d_in[6];
    const float* fc_b  = (const float*)d_in[7];
    const float* L_w   = (const float*)d_in[8];
    const float* L_b   = (const float*)d_in[9];
    float* out = (float*)d_out;

    float* ws      = (float*)d_ws;
    float* fc7     = ws;                          // 24576 f
    float* taub    = ws + 24576;                  // pad to 64
    float* params  = ws + 24640;                  // 32768 f
    unsigned* wfrag1 = (unsigned*)(ws + 57408);   // 4096 u32
    unsigned* wfrag2 = wfrag1 + 4096;             // 40960 u32

    const int B = in_sizes[1];                    // 4096

    precompute_kernel<<<69, 256, 0, stream>>>(w1, w2, fc_w, fc_b, L_w, L_b,
                                              fc7, taub, wfrag1, wfrag2);
    fused_kernel<<<B, 256, 0, stream>>>(input, b1, b2, wfrag1, wfrag2,
                                        fc7, fc_b, taub, params);
    rollout_kernel<<<B / 256, 256, 0, stream>>>(params, y0, out);
}

// Round 8
// 154.770 us; speedup vs baseline: 1.1840x; 1.0119x over previous
//
#include <hip/hip_runtime.h>
#include <math.h>

// ---------------------------------------------------------------------------
// B=4096. conv1 (64,5,7) pad3 + relu + pool4 -> h1 (64,96)
//         conv2 (128,64,5) pad2 + relu + pool4 -> feat (128,24)
//         fc: only cols 0..5 of (404,3072) + tau = feat·(L_w@fc_w) + const.
// Split-bf16 MFMA (hi+lo, 3 mfma/product — REQUIRED precision: rollout
// amplifies param error ~1e6x).
// R8: both convs on v_mfma_f32_32x32x16_bf16 (1015 vs 844 FLOP/cyc/SIMD,
// half the instructions). conv1 K-repacked k'=ic*8+dk (K'=48, taps in
// weight zeros). conv2 = 5 shifted GEMMs over K=64(ic), 20 k-steps of 16.
// C/D (m74/m101): col=lane&31(oc), row=(reg&3)+8*(reg>>2)+4*(lane>>5) ->
// reg-quads = 4 consecutive pos -> pool4 in-register.
// A: row=lane&31, k=(lane>>5)*8+j.  B: col=lane&31, k=(lane>>5)*8+j.
// ---------------------------------------------------------------------------

typedef short bf16x8 __attribute__((ext_vector_type(8)));
typedef float f32x4  __attribute__((ext_vector_type(4)));
typedef float f32x16 __attribute__((ext_vector_type(16)));
typedef int   i32x4  __attribute__((ext_vector_type(4)));

union Frag { int u[4]; i32x4 q; bf16x8 v; };

__device__ __forceinline__ unsigned bf16_rne(float f) {
    unsigned u = __float_as_uint(f);
    return (u + 0x7fffu + ((u >> 16) & 1u)) >> 16;
}
__device__ __forceinline__ unsigned packsplit(float f) {
    unsigned hi = bf16_rne(f);
    float lo = f - __uint_as_float(hi << 16);
    return (hi << 16) | bf16_rne(lo);
}

#define ZERO16 {0.f,0.f,0.f,0.f,0.f,0.f,0.f,0.f,0.f,0.f,0.f,0.f,0.f,0.f,0.f,0.f}

// ---------------------------------------------------------------------------
// Kernel 0 (merged): fc7 (blocks 0..47), taub+wfrag1 (48), wfrag2 (49..68).
//  wfrag1: [ks3][nt2][lane64][part2][4u32]   k'=ks*16+(lane>>5)*8+j -> ic=k'>>3, dk=k'&7
//  wfrag2: [step20][nt4][lane64][part2][4u32] step=dk*4+icc; k_ic=icc*16+(lane>>5)*8+j
// ---------------------------------------------------------------------------
__global__ void precompute_kernel(const float* __restrict__ w1,
                                  const float* __restrict__ w2,
                                  const float* __restrict__ fc_w,
                                  const float* __restrict__ fc_b,
                                  const float* __restrict__ L_w,
                                  const float* __restrict__ L_b,
                                  float* __restrict__ fc7,
                                  float* __restrict__ taub,
                                  unsigned* __restrict__ wfrag1,
                                  unsigned* __restrict__ wfrag2) {
    const int t = threadIdx.x, bb = blockIdx.x;
    if (bb < 48) {
        __shared__ float part[3][64];
        const int k = bb * 64 + (t & 63), jc = t >> 6;
        const int j0 = jc * 101;
        float s = 0.f;
        #pragma unroll 4
        for (int j = j0; j < j0 + 101; ++j) s += L_w[j] * fc_w[j * 3072 + k];
        if (jc) part[jc - 1][t & 63] = s;
        __syncthreads();
        if (jc == 0) {
            const int kk = t & 63;
            float r[8];
            #pragma unroll
            for (int j = 0; j < 6; ++j) r[j] = fc_w[j * 3072 + k];
            r[6] = s + part[0][kk] + part[1][kk] + part[2][kk];
            r[7] = 0.f;
            #pragma unroll
            for (int j = 0; j < 8; ++j) fc7[k * 8 + j] = r[j];
        }
    } else if (bb == 48) {
        if (t < 64) {
            float s = 0.f;
            for (int j = t; j < 404; j += 64) s += L_w[j] * fc_b[j];
            #pragma unroll
            for (int off = 32; off; off >>= 1) s += __shfl_down(s, off);
            if (t == 0) taub[0] = s + L_b[0];
        }
        for (int i = t; i < 768; i += 256) {        // conv1 frags
            const int part = i & 1, lane = (i >> 1) & 63,
                      nt = (i >> 7) & 1, ks = i >> 8;        // 0..2
            const int oc = nt * 32 + (lane & 31);
            unsigned h[8];
            #pragma unroll
            for (int j = 0; j < 8; ++j) {
                const int kp = ks * 16 + (lane >> 5) * 8 + j;  // k' = ic*8+dk
                const int ic = kp >> 3, dk = kp & 7;
                float v = (ic < 5 && dk < 7) ? w1[oc * 35 + ic * 7 + dk] : 0.f;
                unsigned hb = bf16_rne(v);
                if (part) hb = bf16_rne(v - __uint_as_float(hb << 16));
                h[j] = hb;
            }
            #pragma unroll
            for (int wj = 0; wj < 4; ++wj)
                wfrag1[i * 4 + wj] = (h[2 * wj + 1] << 16) | h[2 * wj];
        }
    } else {                                        // conv2 frags: 10240 items
        const int base = (bb - 49) * 512;
        #pragma unroll
        for (int r = 0; r < 2; ++r) {
            const int i = base + r * 256 + t;
            const int part = i & 1, lane = (i >> 1) & 63,
                      nt = (i >> 7) & 3, step = i >> 9;       // 0..19
            const int oc = nt * 32 + (lane & 31);
            const int dk = step >> 2, icc = step & 3;
            unsigned h[8];
            #pragma unroll
            for (int j = 0; j < 8; ++j) {
                const int ic = icc * 16 + (lane >> 5) * 8 + j;  // k = ic
                const float v = w2[oc * 320 + ic * 5 + dk];
                unsigned hb = bf16_rne(v);
                if (part) hb = bf16_rne(v - __uint_as_float(hb << 16));
                h[j] = hb;
            }
            #pragma unroll
            for (int wj = 0; wj < 4; ++wj)
                wfrag2[i * 4 + wj] = (h[2 * wj + 1] << 16) | h[2 * wj];
        }
    }
}

// ---------------------------------------------------------------------------
// Kernel 1: fused conv1+conv2+fc, one batch per block, 4 blocks/CU.
// LDS (38336 B): lds_in u32[6][392] packed (row5=zeros),
//   h1_hi/h1_lo bf16[100][72] (rows 0,1,98,99 halo-zero), red f32[32].
// ---------------------------------------------------------------------------
__global__ __launch_bounds__(256, 4) void fused_kernel(
    const float* __restrict__ input,
    const float* __restrict__ b1,
    const float* __restrict__ b2,
    const unsigned* __restrict__ wfrag1,
    const unsigned* __restrict__ wfrag2,
    const float* __restrict__ fc7,
    const float* __restrict__ fc_b,
    const float* __restrict__ taubp,
    float* __restrict__ params)
{
    __shared__ unsigned lds_in[2352];
    __shared__ __align__(16) unsigned short h1_hi[7200];   // [100][72]
    __shared__ __align__(16) unsigned short h1_lo[7200];
    __shared__ float red[32];

    const int t = threadIdx.x, b = blockIdx.x;
    const int lane = t & 63, w = t >> 6;
    const int lq = lane & 31, hi = lane >> 5;

    // ---- zero lds_in + h1 halo rows (0,1,98,99) ----
    for (int i = t; i < 2352; i += 256) lds_in[i] = 0u;
    if (t < 144) {
        const int r = t / 36, wd = t - r * 36;
        const int row = (r < 2) ? r : 96 + r;
        ((unsigned*)h1_hi)[row * 36 + wd] = 0u;
        ((unsigned*)h1_lo)[row * 36 + wd] = 0u;
    }
    __syncthreads();
    const float* inb = input + (size_t)b * 1920;
    for (int i = t; i < 1920; i += 256) {
        const int ic = i / 384, x = i - ic * 384;
        lds_in[ic * 392 + 3 + x] = packsplit(inb[i]);
    }
    __syncthreads();

    // ------------- conv1: C[pos=384][oc=64], K'=48 (3 ks of 16) -------------
    // wave w owns mtiles w*3..w*3+2 (32 pos each), both oc-ntiles.
    const i32x4* w1f = (const i32x4*)wfrag1;
    Frag c1b[3][2][2];                       // [ks][nt][part]
    #pragma unroll
    for (int ks = 0; ks < 3; ++ks)
        #pragma unroll
        for (int nt = 0; nt < 2; ++nt) {
            const int fi = ((ks * 2 + nt) * 64 + lane) * 2;
            c1b[ks][nt][0].q = w1f[fi];
            c1b[ks][nt][1].q = w1f[fi + 1];
        }
    float b1v[2];
    #pragma unroll
    for (int nt = 0; nt < 2; ++nt) b1v[nt] = b1[nt * 32 + lq];

    // per-lane A base: element (ic = ks*2+hi)*392 + pos, pos = mtile*32+lq
    const unsigned* aB1 = lds_in + hi * 392 + lq;
    #pragma unroll
    for (int m = 0; m < 3; ++m) {
        const int mtile = w * 3 + m;
        f32x16 acc0 = ZERO16, acc1 = ZERO16;
        #pragma unroll
        for (int ks = 0; ks < 3; ++ks) {
            unsigned p[8];
            #pragma unroll
            for (int j = 0; j < 8; ++j) p[j] = aB1[ks * 784 + mtile * 32 + j];
            Frag ah, al;
            #pragma unroll
            for (int wj = 0; wj < 4; ++wj) {
                ah.u[wj] = __builtin_amdgcn_perm(p[2*wj+1], p[2*wj], 0x07060302u);
                al.u[wj] = __builtin_amdgcn_perm(p[2*wj+1], p[2*wj], 0x05040100u);
            }
            acc0 = __builtin_amdgcn_mfma_f32_32x32x16_bf16(ah.v, c1b[ks][0][0].v, acc0, 0, 0, 0);
            acc1 = __builtin_amdgcn_mfma_f32_32x32x16_bf16(ah.v, c1b[ks][1][0].v, acc1, 0, 0, 0);
            acc0 = __builtin_amdgcn_mfma_f32_32x32x16_bf16(ah.v, c1b[ks][0][1].v, acc0, 0, 0, 0);
            acc1 = __builtin_amdgcn_mfma_f32_32x32x16_bf16(ah.v, c1b[ks][1][1].v, acc1, 0, 0, 0);
            acc0 = __builtin_amdgcn_mfma_f32_32x32x16_bf16(al.v, c1b[ks][0][0].v, acc0, 0, 0, 0);
            acc1 = __builtin_amdgcn_mfma_f32_32x32x16_bf16(al.v, c1b[ks][1][0].v, acc1, 0, 0, 0);
        }
        // pool4 + relu + split-write: reg-quad q = rows 8q+4hi+0..3
        #pragma unroll
        for (int q = 0; q < 4; ++q) {
            const int c = mtile * 8 + 2 * q + hi;
            {
                float s = 0.f;
                #pragma unroll
                for (int r4 = 0; r4 < 4; ++r4) s += fmaxf(acc0[q*4+r4] + b1v[0], 0.f);
                const float v = 0.25f * s;
                const unsigned hb = bf16_rne(v);
                h1_hi[(c + 2) * 72 + lq] = (unsigned short)hb;
                h1_lo[(c + 2) * 72 + lq] =
                    (unsigned short)bf16_rne(v - __uint_as_float(hb << 16));
            }
            {
                float s = 0.f;
                #pragma unroll
                for (int r4 = 0; r4 < 4; ++r4) s += fmaxf(acc1[q*4+r4] + b1v[1], 0.f);
                const float v = 0.25f * s;
                const unsigned hb = bf16_rne(v);
                h1_hi[(c + 2) * 72 + 32 + lq] = (unsigned short)hb;
                h1_lo[(c + 2) * 72 + 32 + lq] =
                    (unsigned short)bf16_rne(v - __uint_as_float(hb << 16));
            }
        }
    }
    __syncthreads();

    // ------ conv2: 20 k-steps (dk*4+icc), wave = ntile w, mtiles 0..2 ------
    f32x16 acc2[3] = {ZERO16, ZERO16, ZERO16};

    const i32x4* aH = (const i32x4*)(h1_hi + lq * 72 + hi * 8);
    const i32x4* aL = (const i32x4*)(h1_lo + lq * 72 + hi * 8);
    const i32x4* w2f = (const i32x4*)wfrag2;
    Frag bh2[2], bl2[2];                     // B double-buffer
    Frag a2h[2], a2l[2];                     // A rolling buffer

    {   // prologue: B(step0), A(step0, mt0): offset (0*32+0)*9+0 = 0
        const int fi = (w * 64 + lane) * 2;
        bh2[0].q = w2f[fi];
        bl2[0].q = w2f[fi + 1];
        a2h[0].q = aH[0];
        a2l[0].q = aL[0];
    }

    #pragma unroll
    for (int s = 0; s < 20; ++s) {
        const int sb = s & 1, snb = sb ^ 1;
        if (s < 19) {
            const int fi = (((s + 1) * 4 + w) * 64 + lane) * 2;
            bh2[snb].q = w2f[fi];
            bl2[snb].q = w2f[fi + 1];
        }
        #pragma unroll
        for (int mt = 0; mt < 3; ++mt) {
            const int it = s * 3 + mt, cur = it & 1, nxt = cur ^ 1;
            if (it < 59) {
                const int nit = it + 1, nmt = nit % 3, ns = nit / 3;
                const int off = (nmt * 32 + (ns >> 2)) * 9 + (ns & 3) * 2;
                a2h[nxt].q = aH[off];
                a2l[nxt].q = aL[off];
            }
            acc2[mt] = __builtin_amdgcn_mfma_f32_32x32x16_bf16(a2h[cur].v, bh2[sb].v, acc2[mt], 0, 0, 0);
            acc2[mt] = __builtin_amdgcn_mfma_f32_32x32x16_bf16(a2h[cur].v, bl2[sb].v, acc2[mt], 0, 0, 0);
            acc2[mt] = __builtin_amdgcn_mfma_f32_32x32x16_bf16(a2l[cur].v, bh2[sb].v, acc2[mt], 0, 0, 0);
        }
    }

    // ---- epilogue: bias+relu+pool4 -> feat; fc7 dots ----
    float dot[7] = {0.f, 0.f, 0.f, 0.f, 0.f, 0.f, 0.f};
    {
        const float b2v = b2[w * 32 + lq];
        #pragma unroll
        for (int mt = 0; mt < 3; ++mt) {
            #pragma unroll
            for (int q = 0; q < 4; ++q) {
                float s = 0.f;
                #pragma unroll
                for (int r4 = 0; r4 < 4; ++r4)
                    s += fmaxf(acc2[mt][q*4+r4] + b2v, 0.f);
                s *= 0.25f;
                const int fq = mt * 8 + 2 * q + hi;
                const int idx = (w * 32 + lq) * 24 + fq;
                const f32x4* fp = (const f32x4*)(fc7 + idx * 8);
                const f32x4 f0 = fp[0], f1 = fp[1];
                dot[0] += s * f0[0]; dot[1] += s * f0[1];
                dot[2] += s * f0[2]; dot[3] += s * f0[3];
                dot[4] += s * f1[0]; dot[5] += s * f1[1];
                dot[6] += s * f1[2];
            }
        }
    }

    #pragma unroll
    for (int j = 0; j < 7; ++j) {
        float s = dot[j];
        #pragma unroll
        for (int off = 32; off; off >>= 1) s += __shfl_down(s, off);
        if (lane == 0) red[w * 8 + j] = s;
    }
    __syncthreads();
    if (t < 7) {
        float s = red[t] + red[8 + t] + red[16 + t] + red[24 + t];
        s += (t < 6) ? fc_b[t] : taubp[0];
        params[(size_t)b * 8 + t] = s;
    }
}

// ---------------------------------------------------------------------------
// Kernel 2: DMP rollout — 1 thread per batch element.
// ---------------------------------------------------------------------------
__global__ void rollout_kernel(const float* __restrict__ params,
                               const float* __restrict__ y0,
                               float* __restrict__ out) {
    const int b = blockIdx.x * 256 + threadIdx.x;
    const float* p = params + (size_t)b * 8;
    const float goal = p[0];
    const float w0 = p[1], w1 = p[2], w2 = p[3], w3 = p[4], w4 = p[5];
    const float tau = p[6];
    const float y0v = y0[b];

    const float c0 = 1.0f;
    const float c1 = 0.77880078307140486825f;
    const float c2 = 0.60653065971263342360f;
    const float c3 = 0.47236655274101470714f;
    const float c4 = 0.36787944117144232160f;
    const float inv2s = -0.5f / 11.180339887498949f;
    const float e0 = inv2s * c0, e1 = inv2s * c1, e2 = inv2s * c2,
                e3 = inv2s * c3, e4 = inv2s * c4;

    float x = 1.0f, y = y0v, z = 0.01f * tau;
    const float td = tau * 0.01f;
    const float gmy0 = goal - y0v;
    float* ob = out + (size_t)b * 101;
    ob[0] = y0v;
    for (int s = 1; s <= 100; ++s) {
        x = x - x * td;
        const float d0 = x - c0, d1 = x - c1, d2 = x - c2, d3 = x - c3, d4 = x - c4;
        const float p0 = __expf(e0 * d0 * d0);
        const float p1 = __expf(e1 * d1 * d1);
        const float p2 = __expf(e2 * d2 * d2);
        const float p3 = __expf(e3 * d3 * d3);
        const float p4 = __expf(e4 * d4 * d4);
        const float den = p0 + p1 + p2 + p3 + p4;
        const float num = w0 * p0 + w1 * p1 + w2 * p2 + w3 * p3 + w4 * p4;
        const float fx = (num / den) * x * gmy0;
        const float dz = 25.0f * (6.25f * (goal - y) - z) + fx;
        const float dy = z;
        y += dy * td;
        z += dz * td;
        ob[s] = y;
    }
}

extern "C" void kernel_launch(void* const* d_in, const int* in_sizes, int n_in,
                              void* d_out, int out_size, void* d_ws, size_t ws_size,
                              hipStream_t stream) {
    const float* input = (const float*)d_in[0];
    const float* y0    = (const float*)d_in[1];
    const float* w1    = (const float*)d_in[2];
    const float* b1    = (const float*)d_in[3];
    const float* w2    = (const float*)d_in[4];
    const float* b2    = (const float*)d_in[5];
    const float* fc_w  = (const float*)d_in[6];
    const float* fc_b  = (const float*)d_in[7];
    const float* L_w   = (const float*)d_in[8];
    const float* L_b   = (const float*)d_in[9];
    float* out = (float*)d_out;

    float* ws      = (float*)d_ws;
    float* fc7     = ws;                          // 24576 f
    float* taub    = ws + 24576;                  // pad to 64
    float* params  = ws + 24640;                  // 32768 f
    unsigned* wfrag1 = (unsigned*)(ws + 57408);   // 3072 u32 (pad to 4096)
    unsigned* wfrag2 = wfrag1 + 4096;             // 40960 u32

    const int B = in_sizes[1];                    // 4096

    precompute_kernel<<<69, 256, 0, stream>>>(w1, w2, fc_w, fc_b, L_w, L_b,
                                              fc7, taub, wfrag1, wfrag2);
    fused_kernel<<<B, 256, 0, stream>>>(input, b1, b2, wfrag1, wfrag2,
                                        fc7, fc_b, taub, params);
    rollout_kernel<<<B / 256, 256, 0, stream>>>(params, y0, out);
}